// Round 10
// baseline (652.646 us; speedup 1.0000x reference)
//
#include <hip/hip_runtime.h>
#include <hip/hip_bf16.h>
#include <math.h>

// B=4, N=4096 -> 16384 windows of NHT=16 tokens, MD=128
#define NHT 16
#define MD 128
#define FFD 256
#define NHEAD 4
#define DH 32
#define PED 32
#define ED 64
#define SCALE 0.17677669529663687f
#define LDT 132      // float stride, [16][128] natural tiles
#define LDU2 260     // float stride, FFN hidden [16][256]

typedef __attribute__((ext_vector_type(8))) short bf8;
typedef __attribute__((ext_vector_type(4))) float f32x4;
union U8 { bf8 v; unsigned short s[8]; uint u[4]; uint4 q; };

#define MFMA __builtin_amdgcn_mfma_f32_16x16x32_bf16

__device__ __forceinline__ unsigned short bf1(float a){
  __hip_bfloat16 h = __float2bfloat16(a);
  return *reinterpret_cast<unsigned short*>(&h);
}
__device__ __forceinline__ void splits(float f, unsigned short &h, unsigned short &l){
  __hip_bfloat16 hb = __float2bfloat16(f);
  h = *reinterpret_cast<unsigned short*>(&hb);
  float r = f - __bfloat162float(hb);
  __hip_bfloat16 lb = __float2bfloat16(r);
  l = *reinterpret_cast<unsigned short*>(&lb);
}
__device__ __forceinline__ float silu_f(float x){ return x / (1.f + __expf(-x)); }

// VERIFIED (r1/r6/r7): serial per-row LN on a [16][LDT] natural tile, threads 0..15.
__device__ __forceinline__ void ln_rows(float* buf, const float* __restrict__ g,
                                        const float* __restrict__ b, int tid){
  if (tid < NHT){
    float* row = buf + tid * LDT;
    float s = 0.f, ss = 0.f;
#pragma unroll
    for (int i = 0; i < MD; i += 4){
      float4 v = *(const float4*)(row + i);
      s += v.x + v.y + v.z + v.w;
      ss = fmaf(v.x,v.x, fmaf(v.y,v.y, fmaf(v.z,v.z, fmaf(v.w,v.w, ss))));
    }
    float m   = s * (1.f/MD);
    float var = ss * (1.f/MD) - m*m;
    float r   = rsqrtf(var + 1e-5f);
#pragma unroll
    for (int i = 0; i < MD; i += 4){
      float4 v  = *(const float4*)(row + i);
      float4 gv = *(const float4*)(g + i);
      float4 bv = *(const float4*)(b + i);
      v.x = fmaf((v.x - m) * r, gv.x, bv.x);
      v.y = fmaf((v.y - m) * r, gv.y, bv.y);
      v.z = fmaf((v.z - m) * r, gv.z, bv.z);
      v.w = fmaf((v.w - m) * r, gv.w, bv.w);
      *(float4*)(row + i) = v;
    }
  }
}

// ---- weight pre-pack: fp32 [K][N] -> bf16 B-frag order, hi only; 256 KiB exact ----
// unit u = (nt*KT+kt)*64+lane holds 8 bf16: W[kt*32+(lane>>4)*8 + j][nt*16+(lane&15)]
__global__ __launch_bounds__(256)
void packw(const float* __restrict__ Wq, const float* __restrict__ Wk,
           const float* __restrict__ Wv, const float* __restrict__ Wo,
           const float* __restrict__ W1, const float* __restrict__ W2,
           uint4* __restrict__ ws){
  int id = blockIdx.x * 256 + threadIdx.x;   // 16384 total
  const float* W; int KT, N, u; uint4* dst;
  if      (id < 2048) { W = Wq;  KT = 4; N = 128; dst = ws;         u = id;         }
  else if (id < 4096) { W = Wk;  KT = 4; N = 128; dst = ws + 2048;  u = id - 2048;  }
  else if (id < 6144) { W = Wv;  KT = 4; N = 128; dst = ws + 4096;  u = id - 4096;  }
  else if (id < 8192) { W = Wo;  KT = 4; N = 128; dst = ws + 6144;  u = id - 6144;  }
  else if (id < 12288){ W = W1;  KT = 4; N = 256; dst = ws + 8192;  u = id - 8192;  }
  else                { W = W2;  KT = 8; N = 128; dst = ws + 12288; u = id - 12288; }
  int lane = u & 63, tile = u >> 6;
  int kt = tile % KT, nt = tile / KT;
  int kr  = kt*32 + ((lane >> 4) << 3);
  int col = nt*16 + (lane & 15);
  const float* p = W + (size_t)kr * N + col;
  U8 hi;
#pragma unroll
  for (int j = 0; j < 8; ++j) hi.s[j] = bf1(p[(size_t)j * N]);
  dst[u] = hi.q;
}

// 4 waves per block, one window; waves split GEMM output tiles.
// LN and attention use the session-verified single-wave implementations.
__global__ __launch_bounds__(256)
void nha_mfma4(const float* __restrict__ x, const float* __restrict__ pos1,
               const float* __restrict__ pos2,
               const float* __restrict__ W_in,
               const float* __restrict__ g_in, const float* __restrict__ b_in,
               const float* __restrict__ W_pe, const float* __restrict__ W_bias,
               const float* __restrict__ bq, const float* __restrict__ bk,
               const float* __restrict__ bv, const float* __restrict__ bo,
               const float* __restrict__ g1, const float* __restrict__ b1,
               const float* __restrict__ g2, const float* __restrict__ b2,
               const uint4* __restrict__ wsp, float* __restrict__ out)
{
  const uint4* pWq  = wsp;
  const uint4* pWk  = wsp + 2048;
  const uint4* pWv  = wsp + 4096;
  const uint4* pWo  = wsp + 6144;
  const uint4* pW1  = wsp + 8192;
  const uint4* pW2  = wsp + 12288;

  __shared__ __align__(16) float Ts[NHT*LDT];   // t (post-LN)
  __shared__ __align__(16) float Qs[NHT*LDT];   // q; later o
  __shared__ __align__(16) float Ks[NHT*LDT];
  __shared__ __align__(16) float Vs[NHT*LDT];
  __shared__ __align__(16) float Ys[NHT*LDT];   // y (post-LN1)
  __shared__ __align__(16) float Zs[NHT*LDT];   // y + ffn; final out
  __shared__ __align__(16) float Us[NHT*LDU2];  // FFN hidden
  __shared__ __align__(16) float Bsm[NHEAD*NHT*NHT];

  const int tid  = threadIdx.x;       // 256 threads = 4 waves
  const int wv   = tid >> 6;
  const int lane = tid & 63;
  const int lm   = lane & 15;
  const int lg   = lane >> 4;
  const int wi   = blockIdx.x;
  const f32x4 zero4 = {0.f,0.f,0.f,0.f};

  // ========== Stage A: t = x @ W_in (wave wv: nt = 2wv, 2wv+1) ==========
  bf8 xh[2], xl[2];
  {
    const float* xp = x + (size_t)wi*1024 + lm*ED + lg*8;
#pragma unroll
    for (int kt = 0; kt < 2; ++kt){
      U8 h, l;
#pragma unroll
      for (int j = 0; j < 8; ++j) splits(xp[kt*32 + j], h.s[j], l.s[j]);
      xh[kt] = h.v; xl[kt] = l.v;
    }
  }
#pragma unroll
  for (int s = 0; s < 2; ++s){
    const int nt = wv*2 + s;
    f32x4 acc = zero4;
#pragma unroll
    for (int kt = 0; kt < 2; ++kt){
      const float* wp = W_in + (size_t)(kt*32 + lg*8)*MD + nt*16 + lm;
      U8 w;
#pragma unroll
      for (int j = 0; j < 8; ++j) w.s[j] = bf1(wp[(size_t)j*MD]);
      acc = MFMA(xh[kt], w.v, acc, 0,0,0);
      acc = MFMA(xl[kt], w.v, acc, 0,0,0);
    }
#pragma unroll
    for (int r = 0; r < 4; ++r) Ts[(lg*4+r)*LDT + nt*16+lm] = acc[r];
  }
  __syncthreads();
  ln_rows(Ts, g_in, b_in, tid);       // verified serial-row LN (threads 0..15)
  __syncthreads();

  // ========== t A-frags: read fp32 rows, split in-register (r8-verified pattern) ==========
  bf8 tAh[4], tAl[4];
#pragma unroll
  for (int kt = 0; kt < 4; ++kt){
    const float* rp = Ts + lm*LDT + kt*32 + lg*8;
    float4 a = *(const float4*)rp;
    float4 c = *(const float4*)(rp+4);
    float f[8] = {a.x,a.y,a.z,a.w,c.x,c.y,c.z,c.w};
    U8 h, l;
#pragma unroll
    for (int j = 0; j < 8; ++j) splits(f[j], h.s[j], l.s[j]);
    tAh[kt] = h.v; tAl[kt] = l.v;
  }

  // ========== Q,K,V (wave wv: its 2 nt of each) ==========
#pragma unroll
  for (int s = 0; s < 2; ++s){
    const int nt = wv*2 + s;
    float bb = bq[nt*16+lm];
    f32x4 acc = {bb,bb,bb,bb};
#pragma unroll
    for (int kt = 0; kt < 4; ++kt){
      U8 bh; bh.q = pWq[(nt*4+kt)*64 + lane];
      acc = MFMA(tAh[kt], bh.v, acc, 0,0,0);
      acc = MFMA(tAl[kt], bh.v, acc, 0,0,0);
    }
#pragma unroll
    for (int r = 0; r < 4; ++r) Qs[(lg*4+r)*LDT + nt*16+lm] = acc[r];
  }
#pragma unroll
  for (int s = 0; s < 2; ++s){
    const int nt = wv*2 + s;
    float bb = bk[nt*16+lm];
    f32x4 acc = {bb,bb,bb,bb};
#pragma unroll
    for (int kt = 0; kt < 4; ++kt){
      U8 bh; bh.q = pWk[(nt*4+kt)*64 + lane];
      acc = MFMA(tAh[kt], bh.v, acc, 0,0,0);
      acc = MFMA(tAl[kt], bh.v, acc, 0,0,0);
    }
#pragma unroll
    for (int r = 0; r < 4; ++r) Ks[(lg*4+r)*LDT + nt*16+lm] = acc[r];
  }
#pragma unroll
  for (int s = 0; s < 2; ++s){
    const int nt = wv*2 + s;
    float bb = bv[nt*16+lm];
    f32x4 acc = {bb,bb,bb,bb};
#pragma unroll
    for (int kt = 0; kt < 4; ++kt){
      U8 bh; bh.q = pWv[(nt*4+kt)*64 + lane];
      acc = MFMA(tAh[kt], bh.v, acc, 0,0,0);
      acc = MFMA(tAl[kt], bh.v, acc, 0,0,0);
    }
#pragma unroll
    for (int r = 0; r < 4; ++r) Vs[(lg*4+r)*LDT + nt*16+lm] = acc[r];
  }

  // ========== rel-pos bias: one (qi,ki) pair per thread, all 4 heads ==========
  {
    const int p = tid;
    float p1 = pos1[(size_t)wi*256 + p];
    float p2 = pos2[(size_t)wi*256 + p];
    float a0=0.f, a1=0.f, a2=0.f, a3=0.f;
#pragma unroll
    for (int i = 0; i < PED; ++i){
      float e = fmaf(p1, W_pe[i], p2 * W_pe[PED+i]);
      float sv = silu_f(e);
      a0 = fmaf(sv, W_bias[i*4+0], a0);
      a1 = fmaf(sv, W_bias[i*4+1], a1);
      a2 = fmaf(sv, W_bias[i*4+2], a2);
      a3 = fmaf(sv, W_bias[i*4+3], a3);
    }
    Bsm[0*256 + p] = a0; Bsm[1*256 + p] = a1; Bsm[2*256 + p] = a2; Bsm[3*256 + p] = a3;
  }
  __syncthreads();

  // ========== attention: r8-VERIFIED 64-lane scalar block (wave 0 only) ==========
  if (tid < 64){
    const int h  = tid >> 4;
    const int qi = tid & 15;
    const float* qrow = Qs + qi*LDT + h*DH;
    float qf[DH];
#pragma unroll
    for (int d = 0; d < DH; d += 4){
      float4 v = *(const float4*)(qrow + d);
      qf[d] = v.x; qf[d+1] = v.y; qf[d+2] = v.z; qf[d+3] = v.w;
    }
    float sc[NHT];
#pragma unroll
    for (int ki = 0; ki < NHT; ++ki){
      const float* krow = Ks + ki*LDT + h*DH;
      float dot = 0.f;
#pragma unroll
      for (int d = 0; d < DH; d += 4){
        float4 kv = *(const float4*)(krow + d);
        dot = fmaf(qf[d], kv.x, dot);   dot = fmaf(qf[d+1], kv.y, dot);
        dot = fmaf(qf[d+2], kv.z, dot); dot = fmaf(qf[d+3], kv.w, dot);
      }
      sc[ki] = fmaf(dot, SCALE, Bsm[h*256 + qi*16 + ki]);
    }
    float mx = sc[0];
#pragma unroll
    for (int ki = 1; ki < NHT; ++ki) mx = fmaxf(mx, sc[ki]);
    float sum = 0.f;
#pragma unroll
    for (int ki = 0; ki < NHT; ++ki){ sc[ki] = __expf(sc[ki]-mx); sum += sc[ki]; }
    const float inv = 1.f/sum;
    float of[DH];
#pragma unroll
    for (int d = 0; d < DH; ++d) of[d] = 0.f;
#pragma unroll
    for (int ki = 0; ki < NHT; ++ki){
      const float* vrow = Vs + ki*LDT + h*DH;
      const float a = sc[ki];
#pragma unroll
      for (int d = 0; d < DH; d += 4){
        float4 vv = *(const float4*)(vrow + d);
        of[d]   = fmaf(a, vv.x, of[d]);   of[d+1] = fmaf(a, vv.y, of[d+1]);
        of[d+2] = fmaf(a, vv.z, of[d+2]); of[d+3] = fmaf(a, vv.w, of[d+3]);
      }
    }
    float* orow = Qs + qi*LDT + h*DH;   // lane-exclusive slice
#pragma unroll
    for (int d = 0; d < DH; d += 4){
      float4 o4 = { of[d]*inv, of[d+1]*inv, of[d+2]*inv, of[d+3]*inv };
      *(float4*)(orow + d) = o4;
    }
  }
  __syncthreads();

  // ========== att_out = o@Wo + bo, residual -> Ys, LN1 ==========
  bf8 oAh[4], oAl[4];
#pragma unroll
  for (int kt = 0; kt < 4; ++kt){
    const float* rp = Qs + lm*LDT + kt*32 + lg*8;
    float4 a = *(const float4*)rp;
    float4 c = *(const float4*)(rp+4);
    float f[8] = {a.x,a.y,a.z,a.w,c.x,c.y,c.z,c.w};
    U8 h, l;
#pragma unroll
    for (int j = 0; j < 8; ++j) splits(f[j], h.s[j], l.s[j]);
    oAh[kt] = h.v; oAl[kt] = l.v;
  }
#pragma unroll
  for (int s = 0; s < 2; ++s){
    const int nt = wv*2 + s;
    float bb = bo[nt*16+lm];
    f32x4 acc = {bb,bb,bb,bb};
#pragma unroll
    for (int kt = 0; kt < 4; ++kt){
      U8 bh; bh.q = pWo[(nt*4+kt)*64 + lane];
      acc = MFMA(oAh[kt], bh.v, acc, 0,0,0);
      acc = MFMA(oAl[kt], bh.v, acc, 0,0,0);
    }
#pragma unroll
    for (int r = 0; r < 4; ++r)
      Ys[(lg*4+r)*LDT + nt*16+lm] = acc[r] + Ts[(lg*4+r)*LDT + nt*16+lm];
  }
  __syncthreads();
  ln_rows(Ys, g1, b1, tid);
  __syncthreads();

  // ========== FFN1: each wave 4 nt1 tiles -> Us ==========
  bf8 yAh[4], yAl[4];
#pragma unroll
  for (int kt = 0; kt < 4; ++kt){
    const float* rp = Ys + lm*LDT + kt*32 + lg*8;
    float4 a = *(const float4*)rp;
    float4 c = *(const float4*)(rp+4);
    float f[8] = {a.x,a.y,a.z,a.w,c.x,c.y,c.z,c.w};
    U8 h, l;
#pragma unroll
    for (int j = 0; j < 8; ++j) splits(f[j], h.s[j], l.s[j]);
    yAh[kt] = h.v; yAl[kt] = l.v;
  }
#pragma unroll
  for (int s = 0; s < 4; ++s){
    const int nt1 = wv*4 + s;
    f32x4 a = zero4;
#pragma unroll
    for (int kt = 0; kt < 4; ++kt){
      U8 bh; bh.q = pW1[(nt1*4+kt)*64 + lane];
      a = MFMA(yAh[kt], bh.v, a, 0,0,0);
      a = MFMA(yAl[kt], bh.v, a, 0,0,0);
    }
#pragma unroll
    for (int r = 0; r < 4; ++r)
      Us[(lg*4+r)*LDU2 + nt1*16+lm] = silu_f(a[r]);
  }
  __syncthreads();

  // ========== FFN2: each wave 2 nt; residual -> Zs, LN2, store ==========
  f32x4 acc2[2] = {zero4, zero4};
#pragma unroll
  for (int kt2 = 0; kt2 < 8; ++kt2){
    bf8 uh, ul;
    {
      const float* rp = Us + lm*LDU2 + kt2*32 + lg*8;
      float4 a = *(const float4*)rp;
      float4 c = *(const float4*)(rp+4);
      float f[8] = {a.x,a.y,a.z,a.w,c.x,c.y,c.z,c.w};
      U8 h, l;
#pragma unroll
      for (int j = 0; j < 8; ++j) splits(f[j], h.s[j], l.s[j]);
      uh = h.v; ul = l.v;
    }
#pragma unroll
    for (int s = 0; s < 2; ++s){
      const int nt = wv*2 + s;
      U8 bh; bh.q = pW2[(nt*8+kt2)*64 + lane];
      acc2[s] = MFMA(uh, bh.v, acc2[s], 0,0,0);
      acc2[s] = MFMA(ul, bh.v, acc2[s], 0,0,0);
    }
  }
#pragma unroll
  for (int s = 0; s < 2; ++s){
    const int nt = wv*2 + s;
#pragma unroll
    for (int r = 0; r < 4; ++r)
      Zs[(lg*4+r)*LDT + nt*16+lm] = acc2[s][r] + Ys[(lg*4+r)*LDT + nt*16+lm];
  }
  __syncthreads();
  ln_rows(Zs, g2, b2, tid);
  __syncthreads();

  float* op = out + (size_t)wi*(NHT*MD);
  for (int i = tid; i < NHT*MD; i += 256)
    op[i] = Zs[(i>>7)*LDT + (i&127)];
}

extern "C" void kernel_launch(void* const* d_in, const int* in_sizes, int n_in,
                              void* d_out, int out_size, void* d_ws, size_t ws_size,
                              hipStream_t stream) {
  const float* x     = (const float*)d_in[0];
  const float* pos1  = (const float*)d_in[1];
  const float* pos2  = (const float*)d_in[2];
  const float* W_in  = (const float*)d_in[3];
  const float* g_in  = (const float*)d_in[4];
  const float* b_in  = (const float*)d_in[5];
  const float* W_pe  = (const float*)d_in[6];
  const float* W_bias= (const float*)d_in[7];
  const float* Wq    = (const float*)d_in[8];
  const float* bq    = (const float*)d_in[9];
  const float* Wk    = (const float*)d_in[10];
  const float* bk    = (const float*)d_in[11];
  const float* Wv    = (const float*)d_in[12];
  const float* bv    = (const float*)d_in[13];
  const float* Wo    = (const float*)d_in[14];
  const float* bo    = (const float*)d_in[15];
  const float* W1    = (const float*)d_in[16];
  const float* W2    = (const float*)d_in[17];
  const float* g1    = (const float*)d_in[18];
  const float* b1    = (const float*)d_in[19];
  const float* g2    = (const float*)d_in[20];
  const float* b2    = (const float*)d_in[21];
  float* out = (float*)d_out;
  uint4* ws  = (uint4*)d_ws;   // 16384 * 16B = 262144 B exactly

  packw<<<64, 256, 0, stream>>>(Wq, Wk, Wv, Wo, W1, W2, ws);

  const int nwin = in_sizes[0] / (NHT * ED);   // 16384
  nha_mfma4<<<nwin, 256, 0, stream>>>(x, pos1, pos2, W_in, g_in, b_in, W_pe, W_bias,
                                      bq, bk, bv, bo, g1, b1, g2, b2, ws, out);
}

// Round 11
// 452.580 us; speedup vs baseline: 1.4421x; 1.4421x over previous
//
#include <hip/hip_runtime.h>
#include <hip/hip_bf16.h>
#include <math.h>

// B=4, N=4096 -> 16384 windows of NHT=16 tokens, MD=128
#define NHT 16
#define MD 128
#define FFD 256
#define NHEAD 4
#define DH 32
#define PED 32
#define ED 64
#define SCALE 0.17677669529663687f
#define SCB 136      // short stride, bf16 [16][128] tiles (272 B rows, 16B-aligned)
#define SCU 40       // short stride, FFN u chunk (80 B rows)

typedef __attribute__((ext_vector_type(8))) short bf8;
typedef __attribute__((ext_vector_type(4))) float f32x4;
union U8 { bf8 v; unsigned short s[8]; uint u[4]; uint4 q; };

#define MFMA __builtin_amdgcn_mfma_f32_16x16x32_bf16

__device__ __forceinline__ unsigned short bf1(float a){
  __hip_bfloat16 h = __float2bfloat16(a);
  return *reinterpret_cast<unsigned short*>(&h);
}
__device__ __forceinline__ float bfh2f(unsigned short s){
  __hip_bfloat16 h = *reinterpret_cast<__hip_bfloat16*>(&s);
  return __bfloat162float(h);
}
__device__ __forceinline__ float silu_f(float x){ return x / (1.f + __expf(-x)); }

// VERIFIED (r8): butterfly LN on MFMA C-layout tile (lane: rows lg*4+r, cols nt*16+lm)
__device__ __forceinline__ void lnC(float (&C)[8][4], const float* __restrict__ g,
                                    const float* __restrict__ b, int lm){
#pragma unroll
  for (int r = 0; r < 4; ++r){
    float s = 0.f, ss = 0.f;
#pragma unroll
    for (int nt = 0; nt < 8; ++nt){ s += C[nt][r]; ss = fmaf(C[nt][r], C[nt][r], ss); }
#pragma unroll
    for (int m = 1; m < 16; m <<= 1){ s += __shfl_xor(s, m); ss += __shfl_xor(ss, m); }
    float mean = s * (1.f/128.f);
    float var  = ss * (1.f/128.f) - mean*mean;
    float rs   = rsqrtf(var + 1e-5f);
#pragma unroll
    for (int nt = 0; nt < 8; ++nt)
      C[nt][r] = fmaf((C[nt][r] - mean) * rs, g[nt*16+lm], b[nt*16+lm]);
  }
}

// ---- weight pre-pack (verified r5-r10): fp32 [K][N] -> bf16 B-frag order; 256 KiB ----
__global__ __launch_bounds__(256)
void packw(const float* __restrict__ Wq, const float* __restrict__ Wk,
           const float* __restrict__ Wv, const float* __restrict__ Wo,
           const float* __restrict__ W1, const float* __restrict__ W2,
           uint4* __restrict__ ws){
  int id = blockIdx.x * 256 + threadIdx.x;   // 16384 total
  const float* W; int KT, N, u; uint4* dst;
  if      (id < 2048) { W = Wq;  KT = 4; N = 128; dst = ws;         u = id;         }
  else if (id < 4096) { W = Wk;  KT = 4; N = 128; dst = ws + 2048;  u = id - 2048;  }
  else if (id < 6144) { W = Wv;  KT = 4; N = 128; dst = ws + 4096;  u = id - 4096;  }
  else if (id < 8192) { W = Wo;  KT = 4; N = 128; dst = ws + 6144;  u = id - 6144;  }
  else if (id < 12288){ W = W1;  KT = 4; N = 256; dst = ws + 8192;  u = id - 8192;  }
  else                { W = W2;  KT = 8; N = 128; dst = ws + 12288; u = id - 12288; }
  int lane = u & 63, tile = u >> 6;
  int kt = tile % KT, nt = tile / KT;
  int kr  = kt*32 + ((lane >> 4) << 3);
  int col = nt*16 + (lane & 15);
  const float* p = W + (size_t)kr * N + col;
  U8 hi;
#pragma unroll
  for (int j = 0; j < 8; ++j) hi.s[j] = bf1(p[(size_t)j * N]);
  dst[u] = hi.q;
}

// r8 single-wave structure; hi-only activations; bf16 inter-stage LDS tiles.
__global__ __launch_bounds__(64)
void nha_mfma(const float* __restrict__ x, const float* __restrict__ pos1,
              const float* __restrict__ pos2,
              const float* __restrict__ W_in,
              const float* __restrict__ g_in, const float* __restrict__ b_in,
              const float* __restrict__ W_pe, const float* __restrict__ W_bias,
              const float* __restrict__ bq, const float* __restrict__ bk,
              const float* __restrict__ bv, const float* __restrict__ bo,
              const float* __restrict__ g1, const float* __restrict__ b1,
              const float* __restrict__ g2, const float* __restrict__ b2,
              const uint4* __restrict__ wsp, float* __restrict__ out)
{
  const uint4* pWq  = wsp;
  const uint4* pWk  = wsp + 2048;
  const uint4* pWv  = wsp + 4096;
  const uint4* pWo  = wsp + 6144;
  const uint4* pW1  = wsp + 8192;
  const uint4* pW2  = wsp + 12288;

  // dedicated buffers, strictly sequential reuse within each (r8-verified discipline)
  __shared__ __align__(16) unsigned short Qb[NHT*SCB];  // q bf16; later o bf16
  __shared__ __align__(16) unsigned short Kb[NHT*SCB];
  __shared__ __align__(16) unsigned short Vb[NHT*SCB];
  __shared__ __align__(16) unsigned short Tb[NHT*SCB];  // t bounce; later y bounce
  __shared__ __align__(16) unsigned short Ub[NHT*SCU];  // FFN u chunk (32 cols)
  __shared__ __align__(16) float Bsm[NHEAD*NHT*NHT];

  const int tid = threadIdx.x;   // one wave per block/window
  const int wi  = blockIdx.x;
  const int lm  = tid & 15;
  const int lg  = tid >> 4;
  const f32x4 zero4 = {0.f,0.f,0.f,0.f};

  // ========== Stage A: t = x @ W_in (hi-only x, W_in from fp32 global) ==========
  bf8 xA[2];
  {
    const float* xp = x + (size_t)wi*1024 + lm*ED + lg*8;
#pragma unroll
    for (int kt = 0; kt < 2; ++kt){
      U8 h;
#pragma unroll
      for (int j = 0; j < 8; ++j) h.s[j] = bf1(xp[kt*32 + j]);
      xA[kt] = h.v;
    }
  }
  float tC[8][4];
#pragma unroll
  for (int nt = 0; nt < 8; ++nt){
    f32x4 acc = zero4;
#pragma unroll
    for (int kt = 0; kt < 2; ++kt){
      const float* wp = W_in + (size_t)(kt*32 + lg*8)*MD + nt*16 + lm;
      U8 w;
#pragma unroll
      for (int j = 0; j < 8; ++j) w.s[j] = bf1(wp[(size_t)j*MD]);
      acc = MFMA(xA[kt], w.v, acc, 0,0,0);
    }
#pragma unroll
    for (int r = 0; r < 4; ++r) tC[nt][r] = acc[r];
  }
  lnC(tC, g_in, b_in, lm);

  // ========== bounce t (bf16) -> A-frags (direct bf8 reads) ==========
#pragma unroll
  for (int nt = 0; nt < 8; ++nt)
#pragma unroll
    for (int r = 0; r < 4; ++r)
      Tb[(lg*4+r)*SCB + nt*16+lm] = bf1(tC[nt][r]);
  __syncthreads();
  bf8 tA[4];
#pragma unroll
  for (int kt = 0; kt < 4; ++kt)
    tA[kt] = *(const bf8*)(Tb + lm*SCB + kt*32 + lg*8);
  __syncthreads();

  // ========== Q,K,V = t@W + b -> bf16 natural tiles ==========
#pragma unroll
  for (int nt = 0; nt < 8; ++nt){
    float bb = bq[nt*16+lm];
    f32x4 acc = {bb,bb,bb,bb};
#pragma unroll
    for (int kt = 0; kt < 4; ++kt){
      U8 bh; bh.q = pWq[(nt*4+kt)*64 + tid];
      acc = MFMA(tA[kt], bh.v, acc, 0,0,0);
    }
#pragma unroll
    for (int r = 0; r < 4; ++r) Qb[(lg*4+r)*SCB + nt*16+lm] = bf1(acc[r]);
  }
#pragma unroll
  for (int nt = 0; nt < 8; ++nt){
    float bb = bk[nt*16+lm];
    f32x4 acc = {bb,bb,bb,bb};
#pragma unroll
    for (int kt = 0; kt < 4; ++kt){
      U8 bh; bh.q = pWk[(nt*4+kt)*64 + tid];
      acc = MFMA(tA[kt], bh.v, acc, 0,0,0);
    }
#pragma unroll
    for (int r = 0; r < 4; ++r) Kb[(lg*4+r)*SCB + nt*16+lm] = bf1(acc[r]);
  }
#pragma unroll
  for (int nt = 0; nt < 8; ++nt){
    float bb = bv[nt*16+lm];
    f32x4 acc = {bb,bb,bb,bb};
#pragma unroll
    for (int kt = 0; kt < 4; ++kt){
      U8 bh; bh.q = pWv[(nt*4+kt)*64 + tid];
      acc = MFMA(tA[kt], bh.v, acc, 0,0,0);
    }
#pragma unroll
    for (int r = 0; r < 4; ++r) Vb[(lg*4+r)*SCB + nt*16+lm] = bf1(acc[r]);
  }

  // ========== rel-pos bias -> Bsm (fp32, verified) ==========
  for (int p = tid; p < NHT*NHT; p += 64){
    float p1 = pos1[(size_t)wi*256 + p];
    float p2 = pos2[(size_t)wi*256 + p];
    float a0=0.f, a1=0.f, a2=0.f, a3=0.f;
#pragma unroll
    for (int i = 0; i < PED; ++i){
      float e = fmaf(p1, W_pe[i], p2 * W_pe[PED+i]);
      float sv = silu_f(e);
      a0 = fmaf(sv, W_bias[i*4+0], a0);
      a1 = fmaf(sv, W_bias[i*4+1], a1);
      a2 = fmaf(sv, W_bias[i*4+2], a2);
      a3 = fmaf(sv, W_bias[i*4+3], a3);
    }
    Bsm[0*256 + p] = a0; Bsm[1*256 + p] = a1; Bsm[2*256 + p] = a2; Bsm[3*256 + p] = a3;
  }
  __syncthreads();

  // ========== attention: r8-verified 64-lane scalar fp32 body, bf16 loads ==========
  {
    const int h  = tid >> 4;
    const int qi = tid & 15;
    float qf[DH];
    {
      const unsigned short* qp = Qb + qi*SCB + h*DH;
#pragma unroll
      for (int d0 = 0; d0 < DH; d0 += 8){
        U8 u; u.v = *(const bf8*)(qp + d0);
#pragma unroll
        for (int j = 0; j < 8; ++j) qf[d0+j] = bfh2f(u.s[j]);
      }
    }
    float sc[NHT];
#pragma unroll
    for (int ki = 0; ki < NHT; ++ki){
      const unsigned short* kp = Kb + ki*SCB + h*DH;
      float dot = 0.f;
#pragma unroll
      for (int d0 = 0; d0 < DH; d0 += 8){
        U8 u; u.v = *(const bf8*)(kp + d0);
#pragma unroll
        for (int j = 0; j < 8; ++j) dot = fmaf(qf[d0+j], bfh2f(u.s[j]), dot);
      }
      sc[ki] = fmaf(dot, SCALE, Bsm[h*256 + qi*16 + ki]);
    }
    float mx = sc[0];
#pragma unroll
    for (int ki = 1; ki < NHT; ++ki) mx = fmaxf(mx, sc[ki]);
    float sum = 0.f;
#pragma unroll
    for (int ki = 0; ki < NHT; ++ki){ sc[ki] = __expf(sc[ki]-mx); sum += sc[ki]; }
    const float inv = 1.f/sum;
    float of[DH];
#pragma unroll
    for (int d = 0; d < DH; ++d) of[d] = 0.f;
#pragma unroll
    for (int ki = 0; ki < NHT; ++ki){
      const unsigned short* vp = Vb + ki*SCB + h*DH;
      const float a = sc[ki];
#pragma unroll
      for (int d0 = 0; d0 < DH; d0 += 8){
        U8 u; u.v = *(const bf8*)(vp + d0);
#pragma unroll
        for (int j = 0; j < 8; ++j) of[d0+j] = fmaf(a, bfh2f(u.s[j]), of[d0+j]);
      }
    }
    unsigned short* op_ = Qb + qi*SCB + h*DH;   // lane-exclusive slice (o over q)
#pragma unroll
    for (int d = 0; d < DH; ++d) op_[d] = bf1(of[d]*inv);
  }
  __syncthreads();

  // ========== att_out = o@Wo + bo (o A-frags direct from Qb), residual, LN1 ==========
  bf8 oA[4];
#pragma unroll
  for (int kt = 0; kt < 4; ++kt)
    oA[kt] = *(const bf8*)(Qb + lm*SCB + kt*32 + lg*8);
#pragma unroll
  for (int nt = 0; nt < 8; ++nt){
    float bb = bo[nt*16+lm];
    f32x4 acc = {bb,bb,bb,bb};
#pragma unroll
    for (int kt = 0; kt < 4; ++kt){
      U8 bh; bh.q = pWo[(nt*4+kt)*64 + tid];
      acc = MFMA(oA[kt], bh.v, acc, 0,0,0);
    }
#pragma unroll
    for (int r = 0; r < 4; ++r) tC[nt][r] += acc[r];   // y = t + att_out
  }
  lnC(tC, g1, b1, lm);
  __syncthreads();

  // ========== bounce y (bf16) -> A-frags ==========
#pragma unroll
  for (int nt = 0; nt < 8; ++nt)
#pragma unroll
    for (int r = 0; r < 4; ++r)
      Tb[(lg*4+r)*SCB + nt*16+lm] = bf1(tC[nt][r]);
  __syncthreads();
  bf8 yA[4];
#pragma unroll
  for (int kt = 0; kt < 4; ++kt)
    yA[kt] = *(const bf8*)(Tb + lm*SCB + kt*32 + lg*8);
  __syncthreads();

  // ========== FFN1 (silu) interleaved with FFN2 accumulation (hi-only) ==========
  f32x4 acc2[8];
#pragma unroll
  for (int nt = 0; nt < 8; ++nt) acc2[nt] = zero4;
#pragma unroll
  for (int kt2 = 0; kt2 < 8; ++kt2){
#pragma unroll
    for (int sub = 0; sub < 2; ++sub){
      int nt1 = kt2*2 + sub;
      f32x4 a = zero4;
#pragma unroll
      for (int kt = 0; kt < 4; ++kt){
        U8 bh; bh.q = pW1[(nt1*4+kt)*64 + tid];
        a = MFMA(yA[kt], bh.v, a, 0,0,0);
      }
#pragma unroll
      for (int r = 0; r < 4; ++r)
        Ub[(lg*4+r)*SCU + sub*16 + lm] = bf1(silu_f(a[r]));
    }
    __syncthreads();
    bf8 uA = *(const bf8*)(Ub + lm*SCU + lg*8);
    __syncthreads();
#pragma unroll
    for (int nt = 0; nt < 8; ++nt){
      U8 bh; bh.q = pW2[(nt*8+kt2)*64 + tid];
      acc2[nt] = MFMA(uA, bh.v, acc2[nt], 0,0,0);
    }
  }

  // ========== residual2, LN2, store ==========
#pragma unroll
  for (int nt = 0; nt < 8; ++nt)
#pragma unroll
    for (int r = 0; r < 4; ++r) tC[nt][r] += acc2[nt][r];
  lnC(tC, g2, b2, lm);

  float* op = out + (size_t)wi*(NHT*MD);
#pragma unroll
  for (int nt = 0; nt < 8; ++nt)
#pragma unroll
    for (int r = 0; r < 4; ++r)
      op[(lg*4+r)*MD + nt*16+lm] = tC[nt][r];
}

extern "C" void kernel_launch(void* const* d_in, const int* in_sizes, int n_in,
                              void* d_out, int out_size, void* d_ws, size_t ws_size,
                              hipStream_t stream) {
  const float* x     = (const float*)d_in[0];
  const float* pos1  = (const float*)d_in[1];
  const float* pos2  = (const float*)d_in[2];
  const float* W_in  = (const float*)d_in[3];
  const float* g_in  = (const float*)d_in[4];
  const float* b_in  = (const float*)d_in[5];
  const float* W_pe  = (const float*)d_in[6];
  const float* W_bias= (const float*)d_in[7];
  const float* Wq    = (const float*)d_in[8];
  const float* bq    = (const float*)d_in[9];
  const float* Wk    = (const float*)d_in[10];
  const float* bk    = (const float*)d_in[11];
  const float* Wv    = (const float*)d_in[12];
  const float* bv    = (const float*)d_in[13];
  const float* Wo    = (const float*)d_in[14];
  const float* bo    = (const float*)d_in[15];
  const float* W1    = (const float*)d_in[16];
  const float* W2    = (const float*)d_in[17];
  const float* g1    = (const float*)d_in[18];
  const float* b1    = (const float*)d_in[19];
  const float* g2    = (const float*)d_in[20];
  const float* b2    = (const float*)d_in[21];
  float* out = (float*)d_out;
  uint4* ws  = (uint4*)d_ws;   // 16384 * 16B = 262144 B exactly

  packw<<<64, 256, 0, stream>>>(Wq, Wk, Wv, Wo, W1, W2, ws);

  const int nwin = in_sizes[0] / (NHT * ED);   // 16384
  nha_mfma<<<nwin, 64, 0, stream>>>(x, pos1, pos2, W_in, g_in, b_in, W_pe, W_bias,
                                    bq, bk, bv, bo, g1, b1, g2, b2, ws, out);
}

// Round 12
// 448.525 us; speedup vs baseline: 1.4551x; 1.0090x over previous
//
#include <hip/hip_runtime.h>
#include <hip/hip_bf16.h>
#include <math.h>

// B=4, N=4096 -> 16384 windows of NHT=16 tokens, MD=128
#define NHT 16
#define MD 128
#define FFD 256
#define NHEAD 4
#define DH 32
#define PED 32
#define ED 64
#define SCALE 0.17677669529663687f
#define SCB 136      // short stride, bf16 [16][128] tiles (272 B rows)
#define LDT 132      // float stride, fp32 [16][128] tiles
#define SCUF 264     // short stride, full FFN u tile [16][256] (528 B rows)

typedef __attribute__((ext_vector_type(8))) short bf8;
typedef __attribute__((ext_vector_type(4))) float f32x4;
union U8 { bf8 v; unsigned short s[8]; uint u[4]; uint4 q; };

#define MFMA __builtin_amdgcn_mfma_f32_16x16x32_bf16

__device__ __forceinline__ unsigned short bf1(float a){
  __hip_bfloat16 h = __float2bfloat16(a);
  return *reinterpret_cast<unsigned short*>(&h);
}
__device__ __forceinline__ float bfh2f(unsigned short s){
  __hip_bfloat16 h = *reinterpret_cast<__hip_bfloat16*>(&s);
  return __bfloat162float(h);
}
__device__ __forceinline__ float silu_f(float x){ return x / (1.f + __expf(-x)); }

// VERIFIED (r8/r11): butterfly LN on MFMA C-layout tile
__device__ __forceinline__ void lnC(float (&C)[8][4], const float* __restrict__ g,
                                    const float* __restrict__ b, int lm){
#pragma unroll
  for (int r = 0; r < 4; ++r){
    float s = 0.f, ss = 0.f;
#pragma unroll
    for (int nt = 0; nt < 8; ++nt){ s += C[nt][r]; ss = fmaf(C[nt][r], C[nt][r], ss); }
#pragma unroll
    for (int m = 1; m < 16; m <<= 1){ s += __shfl_xor(s, m); ss += __shfl_xor(ss, m); }
    float mean = s * (1.f/128.f);
    float var  = ss * (1.f/128.f) - mean*mean;
    float rs   = rsqrtf(var + 1e-5f);
#pragma unroll
    for (int nt = 0; nt < 8; ++nt)
      C[nt][r] = fmaf((C[nt][r] - mean) * rs, g[nt*16+lm], b[nt*16+lm]);
  }
}

// ---- weight pre-pack (verified r5-r11): fp32 [K][N] -> bf16 B-frag order; 256 KiB ----
__global__ __launch_bounds__(256)
void packw(const float* __restrict__ Wq, const float* __restrict__ Wk,
           const float* __restrict__ Wv, const float* __restrict__ Wo,
           const float* __restrict__ W1, const float* __restrict__ W2,
           uint4* __restrict__ ws){
  int id = blockIdx.x * 256 + threadIdx.x;   // 16384 total
  const float* W; int KT, N, u; uint4* dst;
  if      (id < 2048) { W = Wq;  KT = 4; N = 128; dst = ws;         u = id;         }
  else if (id < 4096) { W = Wk;  KT = 4; N = 128; dst = ws + 2048;  u = id - 2048;  }
  else if (id < 6144) { W = Wv;  KT = 4; N = 128; dst = ws + 4096;  u = id - 4096;  }
  else if (id < 8192) { W = Wo;  KT = 4; N = 128; dst = ws + 6144;  u = id - 6144;  }
  else if (id < 12288){ W = W1;  KT = 4; N = 256; dst = ws + 8192;  u = id - 8192;  }
  else                { W = W2;  KT = 8; N = 128; dst = ws + 12288; u = id - 12288; }
  int lane = u & 63, tile = u >> 6;
  int kt = tile % KT, nt = tile / KT;
  int kr  = kt*32 + ((lane >> 4) << 3);
  int col = nt*16 + (lane & 15);
  const float* p = W + (size_t)kr * N + col;
  U8 hi;
#pragma unroll
  for (int j = 0; j < 8; ++j) hi.s[j] = bf1(p[(size_t)j * N]);
  dst[u] = hi.q;
}

// W_in pack (same frag rule, KT=2, N=128) -> ws + 16384 units; launched only
// when ws_size allows (host-checked).
__global__ __launch_bounds__(256)
void packwin(const float* __restrict__ Win, uint4* __restrict__ ws){
  int u = blockIdx.x * 256 + threadIdx.x;   // 1024 total
  int lane = u & 63, tile = u >> 6;
  int kt = tile % 2, nt = tile / 2;
  int kr  = kt*32 + ((lane >> 4) << 3);
  int col = nt*16 + (lane & 15);
  const float* p = Win + (size_t)kr * MD + col;
  U8 hi;
#pragma unroll
  for (int j = 0; j < 8; ++j) hi.s[j] = bf1(p[(size_t)j * MD]);
  ws[16384 + u] = hi.q;
}

// r11 single-wave structure; fp32 K/V tiles; full-width FFN u (2 barriers).
__global__ __launch_bounds__(64)
void nha_mfma(const float* __restrict__ x, const float* __restrict__ pos1,
              const float* __restrict__ pos2,
              const float* __restrict__ W_in,
              const float* __restrict__ g_in, const float* __restrict__ b_in,
              const float* __restrict__ W_pe, const float* __restrict__ W_bias,
              const float* __restrict__ bq, const float* __restrict__ bk,
              const float* __restrict__ bv, const float* __restrict__ bo,
              const float* __restrict__ g1, const float* __restrict__ b1,
              const float* __restrict__ g2, const float* __restrict__ b2,
              const uint4* __restrict__ wsp, int useWin, float* __restrict__ out)
{
  const uint4* pWq  = wsp;
  const uint4* pWk  = wsp + 2048;
  const uint4* pWv  = wsp + 4096;
  const uint4* pWo  = wsp + 6144;
  const uint4* pW1  = wsp + 8192;
  const uint4* pW2  = wsp + 12288;
  const uint4* pWin = wsp + 16384;

  // dedicated buffers (r8/r11-verified discipline; no aliasing)
  __shared__ __align__(16) unsigned short Qb[NHT*SCB];  // q bf16; later o bf16
  __shared__ __align__(16) float Kf[NHT*LDT];           // K fp32
  __shared__ __align__(16) float Vf[NHT*LDT];           // V fp32
  __shared__ __align__(16) unsigned short Tb[NHT*SCB];  // t bounce; later y bounce
  __shared__ __align__(16) unsigned short Ub[NHT*SCUF]; // FFN u, full width
  __shared__ __align__(16) float Bsm[NHEAD*NHT*NHT];

  const int tid = threadIdx.x;   // one wave per block/window
  const int wi  = blockIdx.x;
  const int lm  = tid & 15;
  const int lg  = tid >> 4;
  const f32x4 zero4 = {0.f,0.f,0.f,0.f};

  // ========== Stage A: t = x @ W_in (hi-only) ==========
  bf8 xA[2];
  {
    const float* xp = x + (size_t)wi*1024 + lm*ED + lg*8;
#pragma unroll
    for (int kt = 0; kt < 2; ++kt){
      U8 h;
#pragma unroll
      for (int j = 0; j < 8; ++j) h.s[j] = bf1(xp[kt*32 + j]);
      xA[kt] = h.v;
    }
  }
  float tC[8][4];
#pragma unroll
  for (int nt = 0; nt < 8; ++nt){
    f32x4 acc = zero4;
#pragma unroll
    for (int kt = 0; kt < 2; ++kt){
      U8 w;
      if (useWin){
        w.q = pWin[(nt*2+kt)*64 + tid];
      } else {
        const float* wp = W_in + (size_t)(kt*32 + lg*8)*MD + nt*16 + lm;
#pragma unroll
        for (int j = 0; j < 8; ++j) w.s[j] = bf1(wp[(size_t)j*MD]);
      }
      acc = MFMA(xA[kt], w.v, acc, 0,0,0);
    }
#pragma unroll
    for (int r = 0; r < 4; ++r) tC[nt][r] = acc[r];
  }
  lnC(tC, g_in, b_in, lm);

  // ========== bounce t (bf16) -> A-frags ==========
#pragma unroll
  for (int nt = 0; nt < 8; ++nt)
#pragma unroll
    for (int r = 0; r < 4; ++r)
      Tb[(lg*4+r)*SCB + nt*16+lm] = bf1(tC[nt][r]);
  __syncthreads();
  bf8 tA[4];
#pragma unroll
  for (int kt = 0; kt < 4; ++kt)
    tA[kt] = *(const bf8*)(Tb + lm*SCB + kt*32 + lg*8);
  __syncthreads();

  // ========== Q (bf16), K,V (fp32) = t@W + b ==========
#pragma unroll
  for (int nt = 0; nt < 8; ++nt){
    float bb = bq[nt*16+lm];
    f32x4 acc = {bb,bb,bb,bb};
#pragma unroll
    for (int kt = 0; kt < 4; ++kt){
      U8 bh; bh.q = pWq[(nt*4+kt)*64 + tid];
      acc = MFMA(tA[kt], bh.v, acc, 0,0,0);
    }
#pragma unroll
    for (int r = 0; r < 4; ++r) Qb[(lg*4+r)*SCB + nt*16+lm] = bf1(acc[r]);
  }
#pragma unroll
  for (int nt = 0; nt < 8; ++nt){
    float bb = bk[nt*16+lm];
    f32x4 acc = {bb,bb,bb,bb};
#pragma unroll
    for (int kt = 0; kt < 4; ++kt){
      U8 bh; bh.q = pWk[(nt*4+kt)*64 + tid];
      acc = MFMA(tA[kt], bh.v, acc, 0,0,0);
    }
#pragma unroll
    for (int r = 0; r < 4; ++r) Kf[(lg*4+r)*LDT + nt*16+lm] = acc[r];
  }
#pragma unroll
  for (int nt = 0; nt < 8; ++nt){
    float bb = bv[nt*16+lm];
    f32x4 acc = {bb,bb,bb,bb};
#pragma unroll
    for (int kt = 0; kt < 4; ++kt){
      U8 bh; bh.q = pWv[(nt*4+kt)*64 + tid];
      acc = MFMA(tA[kt], bh.v, acc, 0,0,0);
    }
#pragma unroll
    for (int r = 0; r < 4; ++r) Vf[(lg*4+r)*LDT + nt*16+lm] = acc[r];
  }

  // ========== rel-pos bias -> Bsm (fp32, verified) ==========
  for (int p = tid; p < NHT*NHT; p += 64){
    float p1 = pos1[(size_t)wi*256 + p];
    float p2 = pos2[(size_t)wi*256 + p];
    float a0=0.f, a1=0.f, a2=0.f, a3=0.f;
#pragma unroll
    for (int i = 0; i < PED; ++i){
      float e = fmaf(p1, W_pe[i], p2 * W_pe[PED+i]);
      float sv = silu_f(e);
      a0 = fmaf(sv, W_bias[i*4+0], a0);
      a1 = fmaf(sv, W_bias[i*4+1], a1);
      a2 = fmaf(sv, W_bias[i*4+2], a2);
      a3 = fmaf(sv, W_bias[i*4+3], a3);
    }
    Bsm[0*256 + p] = a0; Bsm[1*256 + p] = a1; Bsm[2*256 + p] = a2; Bsm[3*256 + p] = a3;
  }
  __syncthreads();

  // ========== attention: r8-verified 64-lane body; Q bf16, K/V fp32 ==========
  {
    const int h  = tid >> 4;
    const int qi = tid & 15;
    float qf[DH];
    {
      const unsigned short* qp = Qb + qi*SCB + h*DH;
#pragma unroll
      for (int d0 = 0; d0 < DH; d0 += 8){
        U8 u; u.v = *(const bf8*)(qp + d0);
#pragma unroll
        for (int j = 0; j < 8; ++j) qf[d0+j] = bfh2f(u.s[j]);
      }
    }
    float sc[NHT];
#pragma unroll
    for (int ki = 0; ki < NHT; ++ki){
      const float* krow = Kf + ki*LDT + h*DH;
      float dot = 0.f;
#pragma unroll
      for (int d = 0; d < DH; d += 4){
        float4 kv = *(const float4*)(krow + d);
        dot = fmaf(qf[d], kv.x, dot);   dot = fmaf(qf[d+1], kv.y, dot);
        dot = fmaf(qf[d+2], kv.z, dot); dot = fmaf(qf[d+3], kv.w, dot);
      }
      sc[ki] = fmaf(dot, SCALE, Bsm[h*256 + qi*16 + ki]);
    }
    float mx = sc[0];
#pragma unroll
    for (int ki = 1; ki < NHT; ++ki) mx = fmaxf(mx, sc[ki]);
    float sum = 0.f;
#pragma unroll
    for (int ki = 0; ki < NHT; ++ki){ sc[ki] = __expf(sc[ki]-mx); sum += sc[ki]; }
    const float inv = 1.f/sum;
    float of[DH];
#pragma unroll
    for (int d = 0; d < DH; ++d) of[d] = 0.f;
#pragma unroll
    for (int ki = 0; ki < NHT; ++ki){
      const float* vrow = Vf + ki*LDT + h*DH;
      const float a = sc[ki];
#pragma unroll
      for (int d = 0; d < DH; d += 4){
        float4 vv = *(const float4*)(vrow + d);
        of[d]   = fmaf(a, vv.x, of[d]);   of[d+1] = fmaf(a, vv.y, of[d+1]);
        of[d+2] = fmaf(a, vv.z, of[d+2]); of[d+3] = fmaf(a, vv.w, of[d+3]);
      }
    }
    unsigned short* op_ = Qb + qi*SCB + h*DH;   // lane-exclusive slice (o over q)
#pragma unroll
    for (int d = 0; d < DH; ++d) op_[d] = bf1(of[d]*inv);
  }
  __syncthreads();

  // ========== att_out = o@Wo + bo, residual, LN1 ==========
  bf8 oA[4];
#pragma unroll
  for (int kt = 0; kt < 4; ++kt)
    oA[kt] = *(const bf8*)(Qb + lm*SCB + kt*32 + lg*8);
#pragma unroll
  for (int nt = 0; nt < 8; ++nt){
    float bb = bo[nt*16+lm];
    f32x4 acc = {bb,bb,bb,bb};
#pragma unroll
    for (int kt = 0; kt < 4; ++kt){
      U8 bh; bh.q = pWo[(nt*4+kt)*64 + tid];
      acc = MFMA(oA[kt], bh.v, acc, 0,0,0);
    }
#pragma unroll
    for (int r = 0; r < 4; ++r) tC[nt][r] += acc[r];   // y = t + att_out
  }
  lnC(tC, g1, b1, lm);
  __syncthreads();

  // ========== bounce y (bf16) -> A-frags ==========
#pragma unroll
  for (int nt = 0; nt < 8; ++nt)
#pragma unroll
    for (int r = 0; r < 4; ++r)
      Tb[(lg*4+r)*SCB + nt*16+lm] = bf1(tC[nt][r]);
  __syncthreads();
  bf8 yA[4];
#pragma unroll
  for (int kt = 0; kt < 4; ++kt)
    yA[kt] = *(const bf8*)(Tb + lm*SCB + kt*32 + lg*8);
  __syncthreads();

  // ========== FFN1 all 16 tiles -> Ub, ONE barrier, then FFN2 ==========
#pragma unroll
  for (int nt1 = 0; nt1 < 16; ++nt1){
    f32x4 a = zero4;
#pragma unroll
    for (int kt = 0; kt < 4; ++kt){
      U8 bh; bh.q = pW1[(nt1*4+kt)*64 + tid];
      a = MFMA(yA[kt], bh.v, a, 0,0,0);
    }
#pragma unroll
    for (int r = 0; r < 4; ++r)
      Ub[(lg*4+r)*SCUF + nt1*16 + lm] = bf1(silu_f(a[r]));
  }
  __syncthreads();
  f32x4 acc2[8];
#pragma unroll
  for (int nt = 0; nt < 8; ++nt) acc2[nt] = zero4;
#pragma unroll
  for (int kt2 = 0; kt2 < 8; ++kt2){
    bf8 uA = *(const bf8*)(Ub + lm*SCUF + kt2*32 + lg*8);
#pragma unroll
    for (int nt = 0; nt < 8; ++nt){
      U8 bh; bh.q = pW2[(nt*8+kt2)*64 + tid];
      acc2[nt] = MFMA(uA, bh.v, acc2[nt], 0,0,0);
    }
  }

  // ========== residual2, LN2, store ==========
#pragma unroll
  for (int nt = 0; nt < 8; ++nt)
#pragma unroll
    for (int r = 0; r < 4; ++r) tC[nt][r] += acc2[nt][r];
  lnC(tC, g2, b2, lm);

  float* op = out + (size_t)wi*(NHT*MD);
#pragma unroll
  for (int nt = 0; nt < 8; ++nt)
#pragma unroll
    for (int r = 0; r < 4; ++r)
      op[(lg*4+r)*MD + nt*16+lm] = tC[nt][r];
}

extern "C" void kernel_launch(void* const* d_in, const int* in_sizes, int n_in,
                              void* d_out, int out_size, void* d_ws, size_t ws_size,
                              hipStream_t stream) {
  const float* x     = (const float*)d_in[0];
  const float* pos1  = (const float*)d_in[1];
  const float* pos2  = (const float*)d_in[2];
  const float* W_in  = (const float*)d_in[3];
  const float* g_in  = (const float*)d_in[4];
  const float* b_in  = (const float*)d_in[5];
  const float* W_pe  = (const float*)d_in[6];
  const float* W_bias= (const float*)d_in[7];
  const float* Wq    = (const float*)d_in[8];
  const float* bq    = (const float*)d_in[9];
  const float* Wk    = (const float*)d_in[10];
  const float* bk    = (const float*)d_in[11];
  const float* Wv    = (const float*)d_in[12];
  const float* bv    = (const float*)d_in[13];
  const float* Wo    = (const float*)d_in[14];
  const float* bo    = (const float*)d_in[15];
  const float* W1    = (const float*)d_in[16];
  const float* W2    = (const float*)d_in[17];
  const float* g1    = (const float*)d_in[18];
  const float* b1    = (const float*)d_in[19];
  const float* g2    = (const float*)d_in[20];
  const float* b2    = (const float*)d_in[21];
  float* out = (float*)d_out;
  uint4* ws  = (uint4*)d_ws;   // 16384 units (256 KiB) + optional 1024 for W_in

  const int useWin = (ws_size >= (size_t)(16384 + 1024) * 16) ? 1 : 0;

  packw<<<64, 256, 0, stream>>>(Wq, Wk, Wv, Wo, W1, W2, ws);
  if (useWin) packwin<<<4, 256, 0, stream>>>(W_in, ws);

  const int nwin = in_sizes[0] / (NHT * ED);   // 16384
  nha_mfma<<<nwin, 64, 0, stream>>>(x, pos1, pos2, W_in, g_in, b_in, W_pe, W_bias,
                                    bq, bk, bv, bo, g1, b1, g2, b2, ws, useWin, out);
}

// Round 13
// 386.707 us; speedup vs baseline: 1.6877x; 1.1599x over previous
//
#include <hip/hip_runtime.h>
#include <hip/hip_bf16.h>
#include <math.h>

// B=4, N=4096 -> 16384 windows of NHT=16 tokens, MD=128
#define NHT 16
#define MD 128
#define FFD 256
#define NHEAD 4
#define DH 32
#define PED 32
#define ED 64
#define SCALE 0.17677669529663687f
#define SCB 136      // short stride, bf16 [16][128] tiles (272 B rows)
#define SCUF 264     // short stride, full FFN u tile [16][256]

typedef __attribute__((ext_vector_type(8))) short bf8;
typedef __attribute__((ext_vector_type(4))) float f32x4;
union U8 { bf8 v; unsigned short s[8]; uint u[4]; uint4 q; };

#define MFMA __builtin_amdgcn_mfma_f32_16x16x32_bf16

__device__ __forceinline__ unsigned short bf1(float a){
  __hip_bfloat16 h = __float2bfloat16(a);
  return *reinterpret_cast<unsigned short*>(&h);
}
__device__ __forceinline__ float bfh2f(unsigned short s){
  __hip_bfloat16 h = *reinterpret_cast<__hip_bfloat16*>(&s);
  return __bfloat162float(h);
}
// silu with fast hardware reciprocal (v_rcp_f32) instead of IEEE divide
__device__ __forceinline__ float silu_f(float x){
  return x * __builtin_amdgcn_rcpf(1.f + __expf(-x));
}

// VERIFIED (r8/r11/r12): butterfly LN on MFMA C-layout tile
__device__ __forceinline__ void lnC(float (&C)[8][4], const float* __restrict__ g,
                                    const float* __restrict__ b, int lm){
#pragma unroll
  for (int r = 0; r < 4; ++r){
    float s = 0.f, ss = 0.f;
#pragma unroll
    for (int nt = 0; nt < 8; ++nt){ s += C[nt][r]; ss = fmaf(C[nt][r], C[nt][r], ss); }
#pragma unroll
    for (int m = 1; m < 16; m <<= 1){ s += __shfl_xor(s, m); ss += __shfl_xor(ss, m); }
    float mean = s * (1.f/128.f);
    float var  = ss * (1.f/128.f) - mean*mean;
    float rs   = rsqrtf(var + 1e-5f);
#pragma unroll
    for (int nt = 0; nt < 8; ++nt)
      C[nt][r] = fmaf((C[nt][r] - mean) * rs, g[nt*16+lm], b[nt*16+lm]);
  }
}

// ---- weight pre-pack (verified r5-r12): fp32 [K][N] -> bf16 B-frag order; 256 KiB ----
__global__ __launch_bounds__(256)
void packw(const float* __restrict__ Wq, const float* __restrict__ Wk,
           const float* __restrict__ Wv, const float* __restrict__ Wo,
           const float* __restrict__ W1, const float* __restrict__ W2,
           uint4* __restrict__ ws){
  int id = blockIdx.x * 256 + threadIdx.x;   // 16384 total
  const float* W; int KT, N, u; uint4* dst;
  if      (id < 2048) { W = Wq;  KT = 4; N = 128; dst = ws;         u = id;         }
  else if (id < 4096) { W = Wk;  KT = 4; N = 128; dst = ws + 2048;  u = id - 2048;  }
  else if (id < 6144) { W = Wv;  KT = 4; N = 128; dst = ws + 4096;  u = id - 4096;  }
  else if (id < 8192) { W = Wo;  KT = 4; N = 128; dst = ws + 6144;  u = id - 6144;  }
  else if (id < 12288){ W = W1;  KT = 4; N = 256; dst = ws + 8192;  u = id - 8192;  }
  else                { W = W2;  KT = 8; N = 128; dst = ws + 12288; u = id - 12288; }
  int lane = u & 63, tile = u >> 6;
  int kt = tile % KT, nt = tile / KT;
  int kr  = kt*32 + ((lane >> 4) << 3);
  int col = nt*16 + (lane & 15);
  const float* p = W + (size_t)kr * N + col;
  U8 hi;
#pragma unroll
  for (int j = 0; j < 8; ++j) hi.s[j] = bf1(p[(size_t)j * N]);
  dst[u] = hi.q;
}

// W_in pack (verified r12) -> ws + 16384 units; launched only if ws_size allows.
__global__ __launch_bounds__(256)
void packwin(const float* __restrict__ Win, uint4* __restrict__ ws){
  int u = blockIdx.x * 256 + threadIdx.x;   // 1024 total
  int lane = u & 63, tile = u >> 6;
  int kt = tile % 2, nt = tile / 2;
  int kr  = kt*32 + ((lane >> 4) << 3);
  int col = nt*16 + (lane & 15);
  const float* p = Win + (size_t)kr * MD + col;
  U8 hi;
#pragma unroll
  for (int j = 0; j < 8; ++j) hi.s[j] = bf1(p[(size_t)j * MD]);
  ws[16384 + u] = hi.q;
}

// r12 single-wave structure; MFMA attention (r2 construction, dedicated buffers).
__global__ __launch_bounds__(64)
void nha_mfma(const float* __restrict__ x, const float* __restrict__ pos1,
              const float* __restrict__ pos2,
              const float* __restrict__ W_in,
              const float* __restrict__ g_in, const float* __restrict__ b_in,
              const float* __restrict__ W_pe, const float* __restrict__ W_bias,
              const float* __restrict__ bq, const float* __restrict__ bk,
              const float* __restrict__ bv, const float* __restrict__ bo,
              const float* __restrict__ g1, const float* __restrict__ b1,
              const float* __restrict__ g2, const float* __restrict__ b2,
              const uint4* __restrict__ wsp, int useWin, float* __restrict__ out)
{
  const uint4* pWq  = wsp;
  const uint4* pWk  = wsp + 2048;
  const uint4* pWv  = wsp + 4096;
  const uint4* pWo  = wsp + 6144;
  const uint4* pW1  = wsp + 8192;
  const uint4* pW2  = wsp + 12288;
  const uint4* pWin = wsp + 16384;

  // dedicated, non-aliased buffers
  __shared__ __align__(16) unsigned short Qb[NHT*SCB];   // q rows; later o rows
  __shared__ __align__(16) unsigned short Kb[NHT*SCB];   // k rows
  __shared__ __align__(16) unsigned short Vt[MD*NHT];    // V^T [d=128][ki=16]
  __shared__ __align__(16) unsigned short Pb[NHT*SCB];   // att rows (per-head 32-col slots)
  __shared__ __align__(16) unsigned short Tb[NHT*SCB];   // t bounce; later y bounce
  __shared__ __align__(16) unsigned short Ub[NHT*SCUF];  // FFN u, full width
  __shared__ __align__(16) float Bsm[NHEAD*NHT*NHT];

  const int tid = threadIdx.x;   // one wave per block/window
  const int wi  = blockIdx.x;
  const int lm  = tid & 15;
  const int lg  = tid >> 4;
  const f32x4 zero4 = {0.f,0.f,0.f,0.f};
  const bf8  zero8 = {0,0,0,0,0,0,0,0};

  // ========== Stage A: t = x @ W_in (hi-only) ==========
  bf8 xA[2];
  {
    const float* xp = x + (size_t)wi*1024 + lm*ED + lg*8;
#pragma unroll
    for (int kt = 0; kt < 2; ++kt){
      U8 h;
#pragma unroll
      for (int j = 0; j < 8; ++j) h.s[j] = bf1(xp[kt*32 + j]);
      xA[kt] = h.v;
    }
  }
  float tC[8][4];
#pragma unroll
  for (int nt = 0; nt < 8; ++nt){
    f32x4 acc = zero4;
#pragma unroll
    for (int kt = 0; kt < 2; ++kt){
      U8 w;
      if (useWin){
        w.q = pWin[(nt*2+kt)*64 + tid];
      } else {
        const float* wp = W_in + (size_t)(kt*32 + lg*8)*MD + nt*16 + lm;
#pragma unroll
        for (int j = 0; j < 8; ++j) w.s[j] = bf1(wp[(size_t)j*MD]);
      }
      acc = MFMA(xA[kt], w.v, acc, 0,0,0);
    }
#pragma unroll
    for (int r = 0; r < 4; ++r) tC[nt][r] = acc[r];
  }
  lnC(tC, g_in, b_in, lm);

  // ========== bounce t (bf16) -> A-frags ==========
#pragma unroll
  for (int nt = 0; nt < 8; ++nt)
#pragma unroll
    for (int r = 0; r < 4; ++r)
      Tb[(lg*4+r)*SCB + nt*16+lm] = bf1(tC[nt][r]);
  __syncthreads();
  bf8 tA[4];
#pragma unroll
  for (int kt = 0; kt < 4; ++kt)
    tA[kt] = *(const bf8*)(Tb + lm*SCB + kt*32 + lg*8);
  __syncthreads();

  // ========== Q,K (bf16 rows), V (transposed bf16) = t@W + b ==========
#pragma unroll
  for (int nt = 0; nt < 8; ++nt){
    float bb = bq[nt*16+lm];
    f32x4 acc = {bb,bb,bb,bb};
#pragma unroll
    for (int kt = 0; kt < 4; ++kt){
      U8 bh; bh.q = pWq[(nt*4+kt)*64 + tid];
      acc = MFMA(tA[kt], bh.v, acc, 0,0,0);
    }
#pragma unroll
    for (int r = 0; r < 4; ++r) Qb[(lg*4+r)*SCB + nt*16+lm] = bf1(acc[r]);
  }
#pragma unroll
  for (int nt = 0; nt < 8; ++nt){
    float bb = bk[nt*16+lm];
    f32x4 acc = {bb,bb,bb,bb};
#pragma unroll
    for (int kt = 0; kt < 4; ++kt){
      U8 bh; bh.q = pWk[(nt*4+kt)*64 + tid];
      acc = MFMA(tA[kt], bh.v, acc, 0,0,0);
    }
#pragma unroll
    for (int r = 0; r < 4; ++r) Kb[(lg*4+r)*SCB + nt*16+lm] = bf1(acc[r]);
  }
#pragma unroll
  for (int nt = 0; nt < 8; ++nt){
    float bb = bv[nt*16+lm];
    f32x4 acc = {bb,bb,bb,bb};
#pragma unroll
    for (int kt = 0; kt < 4; ++kt){
      U8 bh; bh.q = pWv[(nt*4+kt)*64 + tid];
      acc = MFMA(tA[kt], bh.v, acc, 0,0,0);
    }
    // V^T store: Vt[d][ki], d = col = nt*16+lm, ki = row = lg*4+r
#pragma unroll
    for (int r = 0; r < 4; ++r) Vt[(nt*16+lm)*NHT + lg*4+r] = bf1(acc[r]);
  }

  // ========== rel-pos bias -> Bsm (fp32, rcpf silu) ==========
  for (int p = tid; p < NHT*NHT; p += 64){
    float p1 = pos1[(size_t)wi*256 + p];
    float p2 = pos2[(size_t)wi*256 + p];
    float a0=0.f, a1=0.f, a2=0.f, a3=0.f;
#pragma unroll
    for (int i = 0; i < PED; ++i){
      float e = fmaf(p1, W_pe[i], p2 * W_pe[PED+i]);
      float sv = silu_f(e);
      a0 = fmaf(sv, W_bias[i*4+0], a0);
      a1 = fmaf(sv, W_bias[i*4+1], a1);
      a2 = fmaf(sv, W_bias[i*4+2], a2);
      a3 = fmaf(sv, W_bias[i*4+3], a3);
    }
    Bsm[0*256 + p] = a0; Bsm[1*256 + p] = a1; Bsm[2*256 + p] = a2; Bsm[3*256 + p] = a3;
  }
  __syncthreads();

  // ========== attention via MFMA (r2 construction, dedicated buffers) ==========
  // S_h = Q_h @ K_h^T : A-frag = Q row lm cols h*32+lg*8 ; B-frag = K row lm (K^T cols)
  bf8 qA[4], kB[4];
#pragma unroll
  for (int h = 0; h < 4; ++h){
    qA[h] = *(const bf8*)(Qb + lm*SCB + h*32 + lg*8);
    kB[h] = *(const bf8*)(Kb + lm*SCB + h*32 + lg*8);
  }
#pragma unroll
  for (int h = 0; h < 4; ++h){
    f32x4 s = MFMA(qA[h], kB[h], zero4, 0,0,0);
    // softmax over ki (= lm lanes), rows qi = lg*4+r — lnC's verified butterfly
#pragma unroll
    for (int r = 0; r < 4; ++r){
      float v = fmaf(s[r], SCALE, Bsm[h*256 + (lg*4+r)*16 + lm]);
      float mx = v;
#pragma unroll
      for (int m = 1; m < 16; m <<= 1) mx = fmaxf(mx, __shfl_xor(mx, m));
      float e = __expf(v - mx);
      float sm = e;
#pragma unroll
      for (int m = 1; m < 16; m <<= 1) sm += __shfl_xor(sm, m);
      Pb[(lg*4+r)*SCB + h*32 + lm] = bf1(e * __builtin_amdgcn_rcpf(sm));
    }
  }
  __syncthreads();

  // PV: O_h = P_h @ V_h  (K=32, upper 16 k zeroed via A)
#pragma unroll
  for (int h = 0; h < 4; ++h){
    bf8 aP = *(const bf8*)(Pb + lm*SCB + h*32 + lg*8);
    if (tid >= 32) aP = zero8;        // k = lg*8+j >= 16 -> zero contribution
#pragma unroll
    for (int n2 = 0; n2 < 2; ++n2){
      bf8 vB = *(const bf8*)(Vt + (h*32 + n2*16 + lm)*NHT + (lg & 1)*8);
      if (tid >= 32) vB = zero8;
      f32x4 o = MFMA(aP, vB, zero4, 0,0,0);
      // o rows over Qb (q fully consumed into qA regs)
#pragma unroll
      for (int r = 0; r < 4; ++r)
        Qb[(lg*4+r)*SCB + h*32 + n2*16 + lm] = bf1(o[r]);
    }
  }
  __syncthreads();

  // ========== att_out = o@Wo + bo, residual, LN1 ==========
  bf8 oA[4];
#pragma unroll
  for (int kt = 0; kt < 4; ++kt)
    oA[kt] = *(const bf8*)(Qb + lm*SCB + kt*32 + lg*8);
#pragma unroll
  for (int nt = 0; nt < 8; ++nt){
    float bb = bo[nt*16+lm];
    f32x4 acc = {bb,bb,bb,bb};
#pragma unroll
    for (int kt = 0; kt < 4; ++kt){
      U8 bh; bh.q = pWo[(nt*4+kt)*64 + tid];
      acc = MFMA(oA[kt], bh.v, acc, 0,0,0);
    }
#pragma unroll
    for (int r = 0; r < 4; ++r) tC[nt][r] += acc[r];   // y = t + att_out
  }
  lnC(tC, g1, b1, lm);
  __syncthreads();

  // ========== bounce y (bf16) -> A-frags ==========
#pragma unroll
  for (int nt = 0; nt < 8; ++nt)
#pragma unroll
    for (int r = 0; r < 4; ++r)
      Tb[(lg*4+r)*SCB + nt*16+lm] = bf1(tC[nt][r]);
  __syncthreads();
  bf8 yA[4];
#pragma unroll
  for (int kt = 0; kt < 4; ++kt)
    yA[kt] = *(const bf8*)(Tb + lm*SCB + kt*32 + lg*8);
  __syncthreads();

  // ========== FFN1 all 16 tiles -> Ub, ONE barrier, then FFN2 ==========
#pragma unroll
  for (int nt1 = 0; nt1 < 16; ++nt1){
    f32x4 a = zero4;
#pragma unroll
    for (int kt = 0; kt < 4; ++kt){
      U8 bh; bh.q = pW1[(nt1*4+kt)*64 + tid];
      a = MFMA(yA[kt], bh.v, a, 0,0,0);
    }
#pragma unroll
    for (int r = 0; r < 4; ++r)
      Ub[(lg*4+r)*SCUF + nt1*16 + lm] = bf1(silu_f(a[r]));
  }
  __syncthreads();
  f32x4 acc2[8];
#pragma unroll
  for (int nt = 0; nt < 8; ++nt) acc2[nt] = zero4;
#pragma unroll
  for (int kt2 = 0; kt2 < 8; ++kt2){
    bf8 uA = *(const bf8*)(Ub + lm*SCUF + kt2*32 + lg*8);
#pragma unroll
    for (int nt = 0; nt < 8; ++nt){
      U8 bh; bh.q = pW2[(nt*8+kt2)*64 + tid];
      acc2[nt] = MFMA(uA, bh.v, acc2[nt], 0,0,0);
    }
  }

  // ========== residual2, LN2, store ==========
#pragma unroll
  for (int nt = 0; nt < 8; ++nt)
#pragma unroll
    for (int r = 0; r < 4; ++r) tC[nt][r] += acc2[nt][r];
  lnC(tC, g2, b2, lm);

  float* op = out + (size_t)wi*(NHT*MD);
#pragma unroll
  for (int nt = 0; nt < 8; ++nt)
#pragma unroll
    for (int r = 0; r < 4; ++r)
      op[(lg*4+r)*MD + nt*16+lm] = tC[nt][r];
}

extern "C" void kernel_launch(void* const* d_in, const int* in_sizes, int n_in,
                              void* d_out, int out_size, void* d_ws, size_t ws_size,
                              hipStream_t stream) {
  const float* x     = (const float*)d_in[0];
  const float* pos1  = (const float*)d_in[1];
  const float* pos2  = (const float*)d_in[2];
  const float* W_in  = (const float*)d_in[3];
  const float* g_in  = (const float*)d_in[4];
  const float* b_in  = (const float*)d_in[5];
  const float* W_pe  = (const float*)d_in[6];
  const float* W_bias= (const float*)d_in[7];
  const float* Wq    = (const float*)d_in[8];
  const float* bq    = (const float*)d_in[9];
  const float* Wk    = (const float*)d_in[10];
  const float* bk    = (const float*)d_in[11];
  const float* Wv    = (const float*)d_in[12];
  const float* bv    = (const float*)d_in[13];
  const float* Wo    = (const float*)d_in[14];
  const float* bo    = (const float*)d_in[15];
  const float* W1    = (const float*)d_in[16];
  const float* W2    = (const float*)d_in[17];
  const float* g1    = (const float*)d_in[18];
  const float* b1    = (const float*)d_in[19];
  const float* g2    = (const float*)d_in[20];
  const float* b2    = (const float*)d_in[21];
  float* out = (float*)d_out;
  uint4* ws  = (uint4*)d_ws;   // 16384 units (256 KiB) + optional 1024 for W_in

  const int useWin = (ws_size >= (size_t)(16384 + 1024) * 16) ? 1 : 0;

  packw<<<64, 256, 0, stream>>>(Wq, Wk, Wv, Wo, W1, W2, ws);
  if (useWin) packwin<<<4, 256, 0, stream>>>(W_in, ws);

  const int nwin = in_sizes[0] / (NHT * ED);   // 16384
  nha_mfma<<<nwin, 64, 0, stream>>>(x, pos1, pos2, W_in, g_in, b_in, W_pe, W_bias,
                                    bq, bk, bv, bo, g1, b1, g2, b2, ws, useWin, out);
}